// Round 12
// baseline (547.639 us; speedup 1.0000x reference)
//
#include <hip/hip_runtime.h>
#include <hip/hip_bf16.h>

// ---------------------------------------------------------------------------
// Segment_3DCenter round 12: conv_mfma two-pass hi/lo staging — LDS halves to
// 36.6 KB -> 4 blocks/CU (32 waves/CU): pass A stages hi plane, computes
// ahi*bhi + alo*bhi; pass B restages lo plane into the same buffer, computes
// ahi*blo. Same MFMA/LDS-read counts, double the latency-hiding wave pool.
// x_t eliminated: conv1 stages d-rows from x directly (L2-resident gather);
// sp_prep reads its 14 x values directly. prep loses the transpose role.
// cpr stays deterministic via fpart[d16] slices + fixed-order reduce.
// ---------------------------------------------------------------------------

#define F_SLICE (64 * 16 * 121)          // 123904
#define PKE (64 * 121 * 134 * 16)        // u16 elements per pk plane
#define LHALF 18304                      // LDS halves (52 panels * 352)
#define AREP_CV 36864                    // u16 per conv in arep (36*2*64*8)

typedef _Float16 half8 __attribute__((ext_vector_type(8)));
typedef float float4v __attribute__((ext_vector_type(4)));
typedef unsigned short u16x8 __attribute__((ext_vector_type(8)));
typedef unsigned short u16x4 __attribute__((ext_vector_type(4)));

typedef __attribute__((address_space(1))) unsigned int gu32;
typedef __attribute__((address_space(3))) unsigned int lu32;

union HU { _Float16 h; unsigned short u; };

// ---------------- prep: softmax + weight repacks + arep --------------------
// blocks 0..47: softmax row; 48..69: wrep1/wrep2d; 70..357: arep.
__global__ __launch_bounds__(256) void prep_kernel(
    const float* __restrict__ cpr_w, const float* __restrict__ w3d1,
    const float* __restrict__ w2d45, const float* __restrict__ w3d23,
    float* __restrict__ a_sm, float* __restrict__ wrep1,
    float* __restrict__ wrep2d, unsigned short* __restrict__ arep) {
  const int bx = blockIdx.x, t = threadIdx.x;
  if (bx < 48) {
    __shared__ float red[128];
    const int row = bx;
    float v = (t < 128) ? cpr_w[row * 128 + t] : -3.0e38f;
    if (t < 128) red[t] = v;
    __syncthreads();
    for (int s = 64; s; s >>= 1) {
      if (t < s) red[t] = fmaxf(red[t], red[t + s]);
      __syncthreads();
    }
    float m = red[0];
    __syncthreads();
    float e = (t < 128) ? expf(v - m) : 0.f;
    if (t < 128) red[t] = e;
    __syncthreads();
    for (int s = 64; s; s >>= 1) {
      if (t < s) red[t] += red[t + s];
      __syncthreads();
    }
    if (t < 128) a_sm[row * 128 + t] = e / red[0];
  } else if (bx < 70) {
    int r = (bx - 48) * 256 + t;
    if (r < 1008) {
      int j = r;
      int kw = j % 3; j /= 3;
      int o = j % 8; j /= 8;
      int kh = j % 3; j /= 3;
      int kd = j % 7; j /= 7;
      int gg = j;
      wrep1[r] = w3d1[(gg * 8 + o) * 63 + kd * 9 + kh * 3 + kw];
    } else if (r < 1008 + 4608) {
      int r2 = r - 1008;
      int o = r2 & 15;
      int uv = (r2 >> 4) % 9;
      int ic = (r2 / 144) % 16;
      int layer = r2 / 2304;
      wrep2d[r2] = w2d45[((layer * 16 + o) * 16 + ic) * 9 + uv];
    }
  } else {
    int idx = (bx - 70) * 256 + t;
    if (idx < 2 * AREP_CV) {
      int j = idx & 7;
      int lane = (idx >> 3) & 63;
      int part = (idx >> 9) & 1;
      int rem = idx >> 10;
      int chunk = rem % 36;
      int cv = rem / 36;
      int kw = chunk % 3;
      int grp = chunk / 3;
      int kdp = grp & 3;
      int kh = grp >> 2;
      int m = lane & 15, q = lane >> 4;
      int kd = 2 * kdp + (q >> 1);
      int ic = (q & 1) * 8 + j;
      float w = 0.f;
      if (kd < 7)
        w = w3d23[((cv * 16 + m) * 16 + ic) * 63 + kd * 9 + kh * 3 + kw] *
            256.f;
      _Float16 hi = (_Float16)w;
      HU out;
      out.h = (part == 0) ? hi : (_Float16)(w - (float)hi);
      arep[idx] = out.u;
    }
  }
}

// ---------------- conv1 (ic=1) fp32: x -> pk1 planes (+fused cpr f1) -------
// stages d-rows directly from x[b][d][p] (stride-121 gather, L2-resident).
__global__ __launch_bounds__(256, 4) void conv1_kernel(
    const float* __restrict__ x, const float* __restrict__ wrep,
    const float* __restrict__ bias, const float* __restrict__ al,
    unsigned short* __restrict__ pk_hi, unsigned short* __restrict__ pk_lo,
    float* __restrict__ f_out) {
  __shared__ float in_lds[18][134];
  __shared__ float red[2][16][4];
  const int t = threadIdx.x;
  const int bx = blockIdx.x;
  const int b = blockIdx.y;
  const int h = bx / 3;
  const int w0 = (bx % 3) * 4;
  const int lane = t & 63;
  const int wv = t >> 6;
  const int dh = wv & 1;
  const int dd = lane + (dh << 6);
  const int g = __builtin_amdgcn_readfirstlane(wv >> 1);
  const int oc_base = g << 3;

  float acc[8][4];
#pragma unroll
  for (int o = 0; o < 8; ++o)
#pragma unroll
    for (int c = 0; c < 4; ++c) acc[o][c] = 0.f;

  const int ds = t & 127;
  const int half = t >> 7;

  for (int r = half; r < 18; r += 2) {
    int hr = r / 6;
    int wc = r - hr * 6;
    int hh = h - 1 + hr;
    int ww = w0 - 1 + wc;
    bool ok = (hh >= 0) & (hh < 11) & (ww >= 0) & (ww < 11);
    const float* src = x + (size_t)b * 15488 + hh * 11 + ww;  // + d*121
    float v = 0.f;
    if (ok && ds >= 3) v = src[(ds - 3) * 121];
    in_lds[r][ds] = v;
    if (ds < 6) {
      float v2 = 0.f;
      if (ok && ds < 3) v2 = src[(125 + ds) * 121];
      in_lds[r][128 + ds] = v2;
    }
  }
  __syncthreads();
  const float* wbase = wrep + g * 504;
#pragma unroll
  for (int kd = 0; kd < 7; ++kd) {
#pragma unroll
    for (int kh = 0; kh < 3; ++kh) {
      float ws[24];
      const float* wp = wbase + kd * 72 + kh * 24;
#pragma unroll
      for (int j = 0; j < 24; ++j) ws[j] = wp[j];
      float v[6];
#pragma unroll
      for (int qq = 0; qq < 6; ++qq) v[qq] = in_lds[kh * 6 + qq][dd + kd];
#pragma unroll
      for (int o = 0; o < 8; ++o)
#pragma unroll
        for (int kw = 0; kw < 3; ++kw) {
          float wv_ = ws[o * 3 + kw];
#pragma unroll
          for (int c = 0; c < 4; ++c)
            acc[o][c] = fmaf(wv_, v[kw + c], acc[o][c]);
        }
    }
  }

  const int p0 = h * 11 + w0;
#pragma unroll
  for (int o = 0; o < 8; ++o) {
    float bv = bias[oc_base + o];
#pragma unroll
    for (int c = 0; c < 4; ++c) acc[o][c] = fmaxf(acc[o][c] + bv, 0.f);
  }
#pragma unroll
  for (int c = 0; c < 4; ++c) {
    if (w0 + c < 11) {
      u16x8 hi8, lo8;
#pragma unroll
      for (int o = 0; o < 8; ++o) {
        float s = acc[o][c] * 256.f;
        _Float16 hh = (_Float16)s;
        HU a, bb;
        a.h = hh;
        bb.h = (_Float16)(s - (float)hh);
        hi8[o] = a.u;
        lo8[o] = bb.u;
      }
      size_t base = (((size_t)b * 121 + p0 + c) * 134 + dd + 3) * 16 + oc_base;
      *(u16x8*)&pk_hi[base] = hi8;
      *(u16x8*)&pk_lo[base] = lo8;
    }
  }
  if (dd < 3) {
    u16x8 z = {0, 0, 0, 0, 0, 0, 0, 0};
#pragma unroll
    for (int c = 0; c < 4; ++c) {
      if (w0 + c < 11) {
        size_t b0 = (((size_t)b * 121 + p0 + c) * 134 + dd) * 16 + oc_base;
        size_t b1 =
            (((size_t)b * 121 + p0 + c) * 134 + 131 + dd) * 16 + oc_base;
        *(u16x8*)&pk_hi[b0] = z;
        *(u16x8*)&pk_lo[b0] = z;
        *(u16x8*)&pk_hi[b1] = z;
        *(u16x8*)&pk_lo[b1] = z;
      }
    }
  }
  float alv[8];
#pragma unroll
  for (int o = 0; o < 8; ++o) alv[o] = al[(oc_base + o) * 128 + dd];
#pragma unroll
  for (int o = 0; o < 8; ++o) {
#pragma unroll
    for (int c = 0; c < 4; ++c) {
      float pv = acc[o][c] * alv[o];
#pragma unroll
      for (int off = 32; off; off >>= 1) pv += __shfl_down(pv, off, 64);
      if (lane == 0) red[dh][oc_base + o][c] = pv;
    }
  }
  __syncthreads();
  if (t < 64) {
    int oc = t >> 2, c = t & 3;
    if (w0 + c < 11)
      f_out[((size_t)b * 16 + oc) * 121 + p0 + c] =
          fmaxf(red[0][oc][c] + red[1][oc][c], 0.f);
  }
}

// ---------------- conv2/conv3: MFMA f16x2-split, two-pass hi/lo LDS --------
// Block = (bx h-pair, d16, b), 512 thr = 8 waves. LDS: ONE plane of 18304
// halves (36.6 KB -> 4 blocks/CU). Pass A: hi staged, ahi*bhi + alo*bhi;
// pass B: lo restaged, ahi*blo. cpr partials -> fpart[d16] (deterministic).
template <bool WRITE_PK>
__global__ __launch_bounds__(512, 2) void conv_mfma_kernel(
    const unsigned short* __restrict__ pin_hi,
    const unsigned short* __restrict__ pin_lo,
    const unsigned short* __restrict__ arep, const float* __restrict__ bias,
    const float* __restrict__ al, unsigned short* __restrict__ pout_hi,
    unsigned short* __restrict__ pout_lo, float* __restrict__ fpart) {
  __shared__ _Float16 lds[LHALF];
  const int t = threadIdx.x;
  const int bx = blockIdx.x, d16 = blockIdx.y, b = blockIdx.z;
  const int lane = t & 63, wave = t >> 6;
  const int n = lane & 15, q = lane >> 4;
  const int hs = wave >> 2, wg = wave & 3;
  const int h = 2 * bx + hs;  // 0..11 (11 = dummy)

  // staging descriptors: 2288 16-B units per plane
  int goff[5], loff[5];
#pragma unroll
  for (int i = 0; i < 5; ++i) {
    int u = t + i * 512;
    if (u < 2288) {
      int pc = u / 22;
      int dloc = u - pc * 22;
      int panel = pc >> 1, icq = pc & 1;
      int rr = panel / 13, cc = panel - rr * 13;
      int hh = 2 * bx + rr - 1, ww = cc - 1;
      bool ok = (hh >= 0) & (hh < 11) & (ww >= 0) & (ww < 11);
      loff[i] = u * 8;
      goff[i] = ok ? (((b * 121 + hh * 11 + ww) * 134 + d16 * 16 + dloc) * 16 +
                      icq * 8)
                   : -1;
    } else {
      loff[i] = -1;
      goff[i] = -1;
    }
  }

  float bias_r[4], alr[4];
#pragma unroll
  for (int r = 0; r < 4; ++r) {
    bias_r[r] = bias[q * 4 + r];
    alr[r] = al[(q * 4 + r) * 128 + d16 * 16 + n];
  }

  // B-read bases (within-plane addressing identical for both passes)
  const int wl0 = wg * 3;
  int cb[5], cbk[5];
  const int base_qn = (q & 1) * 176 + n * 8 + hs * 4576;
  const int kdh = (lane & 32) ? 8 : 0;
#pragma unroll
  for (int j = 0; j < 5; ++j) {
    int colj = wl0 + j;
    if (colj > 12) colj = 12;  // dummy-only column, result discarded
    cb[j] = base_qn + colj * 352;
    cbk[j] = cb[j] + kdh;
  }

  float4v acc[3];
#pragma unroll
  for (int tt = 0; tt < 3; ++tt) acc[tt] = (float4v){0.f, 0.f, 0.f, 0.f};

  // ---- pass A: stage hi plane ----
#pragma unroll
  for (int i = 0; i < 5; ++i) {
    int lbo = __builtin_amdgcn_readfirstlane((wave << 6) + i * 512);
    if (loff[i] >= 0) {
      if (goff[i] >= 0) {
        __builtin_amdgcn_global_load_lds((const gu32*)&pin_hi[goff[i]],
                                         (lu32*)&lds[(size_t)lbo * 8], 16, 0,
                                         0);
      } else {
        u16x8 z = {0, 0, 0, 0, 0, 0, 0, 0};
        *(u16x8*)&lds[loff[i]] = z;
      }
    }
  }
  __syncthreads();
  // compute A: ahi*bhi + alo*bhi
#pragma unroll
  for (int kh = 0; kh < 3; ++kh) {
#pragma unroll
    for (int kdp = 0; kdp < 4; ++kdp) {
      half8 wv5[5];
#pragma unroll
      for (int j = 0; j < 5; ++j) {
        int a = ((kdp < 3) ? cbk[j] : cb[j]) + kh * 4576 + kdp * 16;
        wv5[j] = *(const half8*)&lds[a];
      }
#pragma unroll
      for (int kw = 0; kw < 3; ++kw) {
        const int c2 = (kh * 4 + kdp) * 3 + kw;
        half8 ahi = *(const half8*)&arep[((c2 * 2 + 0) * 64 + lane) * 8];
        half8 alo = *(const half8*)&arep[((c2 * 2 + 1) * 64 + lane) * 8];
#pragma unroll
        for (int tt = 0; tt < 3; ++tt) {
          acc[tt] = __builtin_amdgcn_mfma_f32_16x16x32_f16(ahi, wv5[tt + kw],
                                                           acc[tt], 0, 0, 0);
          acc[tt] = __builtin_amdgcn_mfma_f32_16x16x32_f16(alo, wv5[tt + kw],
                                                           acc[tt], 0, 0, 0);
        }
      }
    }
  }
  __syncthreads();
  // ---- pass B: restage lo plane into the same buffer ----
#pragma unroll
  for (int i = 0; i < 5; ++i) {
    int lbo = __builtin_amdgcn_readfirstlane((wave << 6) + i * 512);
    if (loff[i] >= 0) {
      if (goff[i] >= 0) {
        __builtin_amdgcn_global_load_lds((const gu32*)&pin_lo[goff[i]],
                                         (lu32*)&lds[(size_t)lbo * 8], 16, 0,
                                         0);
      } else {
        u16x8 z = {0, 0, 0, 0, 0, 0, 0, 0};
        *(u16x8*)&lds[loff[i]] = z;
      }
    }
  }
  __syncthreads();
  // compute B: ahi*blo
#pragma unroll
  for (int kh = 0; kh < 3; ++kh) {
#pragma unroll
    for (int kdp = 0; kdp < 4; ++kdp) {
      half8 wv5[5];
#pragma unroll
      for (int j = 0; j < 5; ++j) {
        int a = ((kdp < 3) ? cbk[j] : cb[j]) + kh * 4576 + kdp * 16;
        wv5[j] = *(const half8*)&lds[a];
      }
#pragma unroll
      for (int kw = 0; kw < 3; ++kw) {
        const int c2 = (kh * 4 + kdp) * 3 + kw;
        half8 ahi = *(const half8*)&arep[((c2 * 2 + 0) * 64 + lane) * 8];
#pragma unroll
        for (int tt = 0; tt < 3; ++tt)
          acc[tt] = __builtin_amdgcn_mfma_f32_16x16x32_f16(ahi, wv5[tt + kw],
                                                           acc[tt], 0, 0, 0);
      }
    }
  }

  // ---- epilogue ----
#pragma unroll
  for (int tt = 0; tt < 3; ++tt) {
    const int wl = wg * 3 + tt;
    if (h < 11 && wl < 11) {
      const int p = h * 11 + wl;
      float fr[4];
      u16x4 hi4, lo4;
#pragma unroll
      for (int r = 0; r < 4; ++r) {
        float sv = fmaxf(acc[tt][r] * (1.f / 65536.f) + bias_r[r], 0.f);
        fr[r] = sv * alr[r];
        if (WRITE_PK) {
          float s = sv * 256.f;
          _Float16 hh = (_Float16)s;
          HU a, bb;
          a.h = hh;
          bb.h = (_Float16)(s - (float)hh);
          hi4[r] = a.u;
          lo4[r] = bb.u;
        }
      }
      if (WRITE_PK) {
        size_t base =
            (((size_t)b * 121 + p) * 134 + d16 * 16 + n + 3) * 16 + q * 4;
        *(u16x4*)&pout_hi[base] = hi4;
        *(u16x4*)&pout_lo[base] = lo4;
        u16x4 z = {0, 0, 0, 0};
        if (d16 == 0 && n < 3) {
          size_t hb = (((size_t)b * 121 + p) * 134 + n) * 16 + q * 4;
          *(u16x4*)&pout_hi[hb] = z;
          *(u16x4*)&pout_lo[hb] = z;
        }
        if (d16 == 7 && n >= 13) {
          size_t hb = (((size_t)b * 121 + p) * 134 + n + 118) * 16 + q * 4;
          *(u16x4*)&pout_hi[hb] = z;
          *(u16x4*)&pout_lo[hb] = z;
        }
      }
      // cpr partial: reduce over the 16 d's of this block; one writer/slot
#pragma unroll
      for (int r = 0; r < 4; ++r) {
        float v = fr[r];
        v += __shfl_xor(v, 1, 64);
        v += __shfl_xor(v, 2, 64);
        v += __shfl_xor(v, 4, 64);
        v += __shfl_xor(v, 8, 64);
        if (n == 0)
          fpart[(((size_t)d16 * 64 + b) * 16 + q * 4 + r) * 121 + p] = v;
      }
    }
  }
}

// ---------------- sp path (+sa side-outs, +f4/f5 recompute in LDS) ---------
__global__ __launch_bounds__(128) void sp_prep_kernel(
    const float* __restrict__ f1, const float* __restrict__ fpart1,
    const float* __restrict__ fpart2, const float* __restrict__ x,
    const float* __restrict__ wrep2d, const float* __restrict__ b2d45,
    const float* __restrict__ seg_w, const float* __restrict__ seg_b,
    const float* __restrict__ so_w, const float* __restrict__ so_b,
    const float* __restrict__ sp_wa, const float* __restrict__ sp_ba,
    const float* __restrict__ sp_wb, const float* __restrict__ sp_bb,
    const float* __restrict__ sp_sw, const float* __restrict__ sp_sb,
    float* __restrict__ sa_sd, float* __restrict__ sp_sd) {
  const int b = blockIdx.x, i = blockIdx.y;
  const int t = threadIdx.x;
  __shared__ float fl[16 * 121];
  __shared__ float buf[16 * 121];
  __shared__ float act[121];
  __shared__ float diffs[121];
  __shared__ int sel[5];
  __shared__ float s7[7], xc7[7];
  __shared__ float P[2][7][7];
  __shared__ float y1[16][9];
  __shared__ float y2[16];

  {
    float* ldst = (i < 3) ? fl : buf;
    if (i == 0) {
      const float* fb = f1 + (size_t)b * 16 * 121;
      for (int idx = t; idx < 16 * 121; idx += 128) ldst[idx] = fb[idx];
    } else {
      const float* fp0 = (i == 1) ? fpart1 : fpart2;
      const size_t boff = (size_t)b * 16 * 121;
      for (int idx = t; idx < 16 * 121; idx += 128) {
        float s = 0.f;
#pragma unroll
        for (int d16 = 0; d16 < 8; ++d16)  // fixed order -> deterministic
          s += fp0[(size_t)d16 * F_SLICE + boff + idx];
        ldst[idx] = fmaxf(s, 0.f);
      }
    }
  }
  __syncthreads();

#define CONV2D_LAYER(SRC, DST, L)                                        \
  if (t < 121) {                                                         \
    int h_ = t / 11, w_ = t - h_ * 11;                                   \
    float a_[16];                                                        \
    _Pragma("unroll") for (int o = 0; o < 16; ++o) a_[o] =               \
        b2d45[(L)*16 + o];                                               \
    for (int ic = 0; ic < 16; ++ic) {                                    \
      _Pragma("unroll") for (int u = 0; u < 3; ++u) {                    \
        int hh_ = h_ + u - 1;                                            \
        _Pragma("unroll") for (int v = 0; v < 3; ++v) {                  \
          int ww_ = w_ + v - 1;                                          \
          float val_ = (hh_ >= 0 && hh_ < 11 && ww_ >= 0 && ww_ < 11)    \
                           ? (SRC)[ic * 121 + hh_ * 11 + ww_]            \
                           : 0.f;                                        \
          const float* wp_ =                                             \
              wrep2d + (((L)*16 + ic) * 9 + u * 3 + v) * 16;             \
          float wr_[16];                                                 \
          _Pragma("unroll") for (int o = 0; o < 16; ++o) wr_[o] = wp_[o];\
          _Pragma("unroll") for (int o = 0; o < 16; ++o) a_[o] =         \
              fmaf(val_, wr_[o], a_[o]);                                 \
        }                                                                \
      }                                                                  \
    }                                                                    \
    _Pragma("unroll") for (int o = 0; o < 16; ++o)(DST)[o * 121 + t] =   \
        fmaxf(a_[o], 0.f);                                               \
  }

  if (i >= 3) {
    CONV2D_LAYER(buf, fl, 0)
    __syncthreads();
    if (i == 4) {
      CONV2D_LAYER(fl, buf, 1)
      __syncthreads();
    }
  }
  const float* F = (i == 4) ? buf : fl;

  if (t < 16) {
    float s = so_b[i * 16 + t];
    const float* swp = so_w + (i * 16 + t) * 16;
    for (int c = 0; c < 16; ++c) s += F[c * 121 + 60] * swp[c];
    sa_sd[((size_t)i * 64 + b) * 16 + t] = s;
  }

  if (t < 121) {
    int h = t / 11, w = t - h * 11;
    float a = seg_b[i];
    const float* sw = seg_w + i * 144;
    for (int ic = 0; ic < 16; ++ic) {
      float w9[9];
#pragma unroll
      for (int j = 0; j < 9; ++j) w9[j] = sw[ic * 9 + j];
#pragma unroll
      for (int u = 0; u < 3; ++u) {
        int hh = h + u - 1;
#pragma unroll
        for (int v = 0; v < 3; ++v) {
          int ww = w + v - 1;
          if (hh >= 0 && hh < 11 && ww >= 0 && ww < 11)
            a = fmaf(F[ic * 121 + hh * 11 + ww], w9[u * 3 + v], a);
        }
      }
    }
    act[t] = a;
  }
  __syncthreads();
  if (t < 121) diffs[t] = fabsf(act[t] - act[60]);
  __syncthreads();

  for (int k = 0; k < 5; ++k) {
    if (t < 64) {
      float d0 = diffs[t];
      int i0 = t;
      float d1 = (t + 64 < 121) ? diffs[t + 64] : 3.0e38f;
      if (d1 < d0) { d0 = d1; i0 = t + 64; }
#pragma unroll
      for (int off = 32; off; off >>= 1) {
        float od = __shfl_down(d0, off, 64);
        int oi = __shfl_down(i0, off, 64);
        if (od < d0 || (od == d0 && oi < i0)) { d0 = od; i0 = oi; }
      }
      if (t == 0) {
        sel[k] = i0;
        diffs[i0] = 3.0e38f;
      }
    }
    __syncthreads();
  }

  if (t < 7) {
    const float* xb = x + (size_t)b * 15488;  // x[b][d][p]
    float s = 0.f;
    for (int k = 0; k < 5; ++k) s += xb[(61 + t) * 121 + sel[k]];
    s7[t] = s;
    xc7[t] = xb[(61 + t) * 121 + 60];
  }
  __syncthreads();
  if (t < 49) {
    int r = t / 7, c = t - r * 7;
    float d0 = s7[c];
    if (fabsf(d0) < 0.01f) d0 = 0.01f;
    float d1 = xc7[c];
    if (fabsf(d1) < 0.01f) d1 = 0.01f;
    P[0][r][c] = s7[r] / d0;
    P[1][r][c] = xc7[r] / d1;
  }
  __syncthreads();
  for (int item = t; item < 144; item += 128) {
    int ch = item / 9, pos = item - ch * 9;
    int a0 = pos / 3, b0 = pos - a0 * 3;
    float a = sp_ba[i * 16 + ch];
    const float* wa = sp_wa + ((size_t)(i * 16 + ch) * 2) * 9;
#pragma unroll
    for (int icc = 0; icc < 2; ++icc)
#pragma unroll
      for (int u = 0; u < 3; ++u)
#pragma unroll
        for (int v = 0; v < 3; ++v)
          a = fmaf(P[icc][2 * a0 + u][2 * b0 + v], wa[icc * 9 + u * 3 + v], a);
    y1[ch][pos] = fmaxf(a, 0.f);
  }
  __syncthreads();
  if (t < 16) {
    float a = sp_bb[i * 16 + t];
    const float* wb = sp_wb + (size_t)(i * 16 + t) * 16 * 9;
    for (int ch = 0; ch < 16; ++ch)
#pragma unroll
      for (int pos = 0; pos < 9; ++pos)
        a = fmaf(y1[ch][pos], wb[ch * 9 + pos], a);
    y2[t] = fmaxf(a, 0.f);
  }
  __syncthreads();
  if (t < 16) {
    float a = sp_sb[i * 16 + t];
    const float* swp = sp_sw + (size_t)(i * 16 + t) * 16;
    for (int ch = 0; ch < 16; ++ch) a = fmaf(y2[ch], swp[ch], a);
    sp_sd[((size_t)i * 64 + b) * 16 + t] = a;
  }
}

// ---------------- final fuse ------------------------------------------------
__global__ __launch_bounds__(256) void fuse_kernel(
    const float* __restrict__ sa_sd, const float* __restrict__ sp_sd,
    const float* __restrict__ fp, float* __restrict__ out) {
  int g = blockIdx.x * 256 + threadIdx.x;
  if (g >= 1024) return;
  int b = g >> 4, o = g & 15;
  float tot = 0.f;
  for (int i = 0; i < 5; ++i) {
    tot += fp[i] * sa_sd[((size_t)i * 64 + b) * 16 + o];
    tot += fp[5 + i] * sp_sd[((size_t)i * 64 + b) * 16 + o];
  }
  out[g] = tot;
}

extern "C" void kernel_launch(void* const* d_in, const int* in_sizes, int n_in,
                              void* d_out, int out_size, void* d_ws,
                              size_t ws_size, hipStream_t stream) {
  const float* x = (const float*)d_in[0];
  const float* w3d1 = (const float*)d_in[1];
  const float* b3d1 = (const float*)d_in[2];
  const float* w3d23 = (const float*)d_in[3];
  const float* b3d23 = (const float*)d_in[4];
  const float* cpr_w = (const float*)d_in[5];
  const float* w2d45 = (const float*)d_in[6];
  const float* b2d45 = (const float*)d_in[7];
  const float* seg_w = (const float*)d_in[8];
  const float* seg_b = (const float*)d_in[9];
  const float* so_w = (const float*)d_in[10];
  const float* so_b = (const float*)d_in[11];
  const float* sp_wa = (const float*)d_in[12];
  const float* sp_ba = (const float*)d_in[13];
  const float* sp_wb = (const float*)d_in[14];
  const float* sp_bb = (const float*)d_in[15];
  const float* sp_sw = (const float*)d_in[16];
  const float* sp_sb = (const float*)d_in[17];
  const float* fpar = (const float*)d_in[18];

  float* ws = (float*)d_ws;
  float* a_sm = ws;                      // 6144 f
  float* f1 = a_sm + 6144;               // F_SLICE f
  float* fpart1 = f1 + F_SLICE;          // 8*F_SLICE f
  float* fpart2 = fpart1 + 8 * F_SLICE;  // 8*F_SLICE f
  float* sp_sd = fpart2 + 8 * F_SLICE;   // 5120 f
  float* sa_sd = sp_sd + 5120;           // 5120 f
  float* wrep1 = sa_sd + 5120;           // 1024 f
  float* wrep2d = wrep1 + 1024;          // 4608 f
  unsigned short* pk1h = (unsigned short*)(wrep2d + 4608);
  unsigned short* pk1l = pk1h + PKE;
  unsigned short* pk2h = pk1l + PKE;
  unsigned short* pk2l = pk2h + PKE;
  unsigned short* arep = pk2l + PKE;     // 2*AREP_CV u16

  prep_kernel<<<358, 256, 0, stream>>>(cpr_w, w3d1, w2d45, w3d23, a_sm, wrep1,
                                       wrep2d, arep);

  conv1_kernel<<<dim3(33, 64), 256, 0, stream>>>(x, wrep1, b3d1, a_sm, pk1h,
                                                 pk1l, f1);
  conv_mfma_kernel<true><<<dim3(6, 8, 64), 512, 0, stream>>>(
      pk1h, pk1l, arep, b3d23, a_sm + 2048, pk2h, pk2l, fpart1);
  conv_mfma_kernel<false><<<dim3(6, 8, 64), 512, 0, stream>>>(
      pk2h, pk2l, arep + AREP_CV, b3d23 + 16, a_sm + 4096, nullptr, nullptr,
      fpart2);

  sp_prep_kernel<<<dim3(64, 5), 128, 0, stream>>>(
      f1, fpart1, fpart2, x, wrep2d, b2d45, seg_w, seg_b, so_w, so_b, sp_wa,
      sp_ba, sp_wb, sp_bb, sp_sw, sp_sb, sa_sd, sp_sd);
  fuse_kernel<<<4, 256, 0, stream>>>(sa_sd, sp_sd, fpar, (float*)d_out);
}

// Round 13
// 451.704 us; speedup vs baseline: 1.2124x; 1.2124x over previous
//
#include <hip/hip_runtime.h>
#include <hip/hip_bf16.h>

// ---------------------------------------------------------------------------
// Segment_3DCenter round 13: conv_mfma REVERTED to round-11 single-pass
// two-plane form (73 KB LDS, 1 barrier, measured 120 us) — round 12's
// two-pass hi/lo (3 barriers, short compute phases) collapsed achieved
// occupancy to 21% and regressed to 200 us. Keep round 12's orthogonal
// wins: no x_t (conv1 stages from x directly; sp_prep reads x directly;
// prep has no transpose role). cpr deterministic via fpart[d16] slices.
// ---------------------------------------------------------------------------

#define F_SLICE (64 * 16 * 121)          // 123904
#define PKE (64 * 121 * 134 * 16)        // u16 elements per pk plane
#define LHALF 18304                      // LDS halves per part (52*352)
#define AREP_CV 36864                    // u16 per conv in arep (36*2*64*8)

typedef _Float16 half8 __attribute__((ext_vector_type(8)));
typedef float float4v __attribute__((ext_vector_type(4)));
typedef unsigned short u16x8 __attribute__((ext_vector_type(8)));
typedef unsigned short u16x4 __attribute__((ext_vector_type(4)));

typedef __attribute__((address_space(1))) unsigned int gu32;
typedef __attribute__((address_space(3))) unsigned int lu32;

union HU { _Float16 h; unsigned short u; };

// ---------------- prep: softmax + weight repacks + arep --------------------
__global__ __launch_bounds__(256) void prep_kernel(
    const float* __restrict__ cpr_w, const float* __restrict__ w3d1,
    const float* __restrict__ w2d45, const float* __restrict__ w3d23,
    float* __restrict__ a_sm, float* __restrict__ wrep1,
    float* __restrict__ wrep2d, unsigned short* __restrict__ arep) {
  const int bx = blockIdx.x, t = threadIdx.x;
  if (bx < 48) {
    __shared__ float red[128];
    const int row = bx;
    float v = (t < 128) ? cpr_w[row * 128 + t] : -3.0e38f;
    if (t < 128) red[t] = v;
    __syncthreads();
    for (int s = 64; s; s >>= 1) {
      if (t < s) red[t] = fmaxf(red[t], red[t + s]);
      __syncthreads();
    }
    float m = red[0];
    __syncthreads();
    float e = (t < 128) ? expf(v - m) : 0.f;
    if (t < 128) red[t] = e;
    __syncthreads();
    for (int s = 64; s; s >>= 1) {
      if (t < s) red[t] += red[t + s];
      __syncthreads();
    }
    if (t < 128) a_sm[row * 128 + t] = e / red[0];
  } else if (bx < 70) {
    int r = (bx - 48) * 256 + t;
    if (r < 1008) {
      int j = r;
      int kw = j % 3; j /= 3;
      int o = j % 8; j /= 8;
      int kh = j % 3; j /= 3;
      int kd = j % 7; j /= 7;
      int gg = j;
      wrep1[r] = w3d1[(gg * 8 + o) * 63 + kd * 9 + kh * 3 + kw];
    } else if (r < 1008 + 4608) {
      int r2 = r - 1008;
      int o = r2 & 15;
      int uv = (r2 >> 4) % 9;
      int ic = (r2 / 144) % 16;
      int layer = r2 / 2304;
      wrep2d[r2] = w2d45[((layer * 16 + o) * 16 + ic) * 9 + uv];
    }
  } else {
    int idx = (bx - 70) * 256 + t;
    if (idx < 2 * AREP_CV) {
      int j = idx & 7;
      int lane = (idx >> 3) & 63;
      int part = (idx >> 9) & 1;
      int rem = idx >> 10;
      int chunk = rem % 36;
      int cv = rem / 36;
      int kw = chunk % 3;
      int grp = chunk / 3;
      int kdp = grp & 3;
      int kh = grp >> 2;
      int m = lane & 15, q = lane >> 4;
      int kd = 2 * kdp + (q >> 1);
      int ic = (q & 1) * 8 + j;
      float w = 0.f;
      if (kd < 7)
        w = w3d23[((cv * 16 + m) * 16 + ic) * 63 + kd * 9 + kh * 3 + kw] *
            256.f;
      _Float16 hi = (_Float16)w;
      HU out;
      out.h = (part == 0) ? hi : (_Float16)(w - (float)hi);
      arep[idx] = out.u;
    }
  }
}

// ---------------- conv1 (ic=1) fp32: x -> pk1 planes (+fused cpr f1) -------
__global__ __launch_bounds__(256, 4) void conv1_kernel(
    const float* __restrict__ x, const float* __restrict__ wrep,
    const float* __restrict__ bias, const float* __restrict__ al,
    unsigned short* __restrict__ pk_hi, unsigned short* __restrict__ pk_lo,
    float* __restrict__ f_out) {
  __shared__ float in_lds[18][134];
  __shared__ float red[2][16][4];
  const int t = threadIdx.x;
  const int bx = blockIdx.x;
  const int b = blockIdx.y;
  const int h = bx / 3;
  const int w0 = (bx % 3) * 4;
  const int lane = t & 63;
  const int wv = t >> 6;
  const int dh = wv & 1;
  const int dd = lane + (dh << 6);
  const int g = __builtin_amdgcn_readfirstlane(wv >> 1);
  const int oc_base = g << 3;

  float acc[8][4];
#pragma unroll
  for (int o = 0; o < 8; ++o)
#pragma unroll
    for (int c = 0; c < 4; ++c) acc[o][c] = 0.f;

  const int ds = t & 127;
  const int half = t >> 7;

  for (int r = half; r < 18; r += 2) {
    int hr = r / 6;
    int wc = r - hr * 6;
    int hh = h - 1 + hr;
    int ww = w0 - 1 + wc;
    bool ok = (hh >= 0) & (hh < 11) & (ww >= 0) & (ww < 11);
    const float* src = x + (size_t)b * 15488 + hh * 11 + ww;  // + d*121
    float v = 0.f;
    if (ok && ds >= 3) v = src[(ds - 3) * 121];
    in_lds[r][ds] = v;
    if (ds < 6) {
      float v2 = 0.f;
      if (ok && ds < 3) v2 = src[(125 + ds) * 121];
      in_lds[r][128 + ds] = v2;
    }
  }
  __syncthreads();
  const float* wbase = wrep + g * 504;
#pragma unroll
  for (int kd = 0; kd < 7; ++kd) {
#pragma unroll
    for (int kh = 0; kh < 3; ++kh) {
      float ws[24];
      const float* wp = wbase + kd * 72 + kh * 24;
#pragma unroll
      for (int j = 0; j < 24; ++j) ws[j] = wp[j];
      float v[6];
#pragma unroll
      for (int qq = 0; qq < 6; ++qq) v[qq] = in_lds[kh * 6 + qq][dd + kd];
#pragma unroll
      for (int o = 0; o < 8; ++o)
#pragma unroll
        for (int kw = 0; kw < 3; ++kw) {
          float wv_ = ws[o * 3 + kw];
#pragma unroll
          for (int c = 0; c < 4; ++c)
            acc[o][c] = fmaf(wv_, v[kw + c], acc[o][c]);
        }
    }
  }

  const int p0 = h * 11 + w0;
#pragma unroll
  for (int o = 0; o < 8; ++o) {
    float bv = bias[oc_base + o];
#pragma unroll
    for (int c = 0; c < 4; ++c) acc[o][c] = fmaxf(acc[o][c] + bv, 0.f);
  }
#pragma unroll
  for (int c = 0; c < 4; ++c) {
    if (w0 + c < 11) {
      u16x8 hi8, lo8;
#pragma unroll
      for (int o = 0; o < 8; ++o) {
        float s = acc[o][c] * 256.f;
        _Float16 hh = (_Float16)s;
        HU a, bb;
        a.h = hh;
        bb.h = (_Float16)(s - (float)hh);
        hi8[o] = a.u;
        lo8[o] = bb.u;
      }
      size_t base = (((size_t)b * 121 + p0 + c) * 134 + dd + 3) * 16 + oc_base;
      *(u16x8*)&pk_hi[base] = hi8;
      *(u16x8*)&pk_lo[base] = lo8;
    }
  }
  if (dd < 3) {
    u16x8 z = {0, 0, 0, 0, 0, 0, 0, 0};
#pragma unroll
    for (int c = 0; c < 4; ++c) {
      if (w0 + c < 11) {
        size_t b0 = (((size_t)b * 121 + p0 + c) * 134 + dd) * 16 + oc_base;
        size_t b1 =
            (((size_t)b * 121 + p0 + c) * 134 + 131 + dd) * 16 + oc_base;
        *(u16x8*)&pk_hi[b0] = z;
        *(u16x8*)&pk_lo[b0] = z;
        *(u16x8*)&pk_hi[b1] = z;
        *(u16x8*)&pk_lo[b1] = z;
      }
    }
  }
  float alv[8];
#pragma unroll
  for (int o = 0; o < 8; ++o) alv[o] = al[(oc_base + o) * 128 + dd];
#pragma unroll
  for (int o = 0; o < 8; ++o) {
#pragma unroll
    for (int c = 0; c < 4; ++c) {
      float pv = acc[o][c] * alv[o];
#pragma unroll
      for (int off = 32; off; off >>= 1) pv += __shfl_down(pv, off, 64);
      if (lane == 0) red[dh][oc_base + o][c] = pv;
    }
  }
  __syncthreads();
  if (t < 64) {
    int oc = t >> 2, c = t & 3;
    if (w0 + c < 11)
      f_out[((size_t)b * 16 + oc) * 121 + p0 + c] =
          fmaxf(red[0][oc][c] + red[1][oc][c], 0.f);
  }
}

// ---------------- conv2/conv3: MFMA f16x2-split, window-reuse K-loop -------
// (round-11 form: both hi/lo planes staged once, single barrier, 73 KB LDS)
template <bool WRITE_PK>
__global__ __launch_bounds__(512, 2) void conv_mfma_kernel(
    const unsigned short* __restrict__ pin_hi,
    const unsigned short* __restrict__ pin_lo,
    const unsigned short* __restrict__ arep, const float* __restrict__ bias,
    const float* __restrict__ al, unsigned short* __restrict__ pout_hi,
    unsigned short* __restrict__ pout_lo, float* __restrict__ fpart) {
  __shared__ _Float16 lds[2 * LHALF];
  const int t = threadIdx.x;
  const int bx = blockIdx.x, d16 = blockIdx.y, b = blockIdx.z;
  const int lane = t & 63, wave = t >> 6;
  const int n = lane & 15, q = lane >> 4;
  const int hs = wave >> 2, wg = wave & 3;
  const int h = 2 * bx + hs;  // 0..11 (11 = dummy)

#pragma unroll
  for (int i = 0; i < 9; ++i) {
    int u = t + i * 512;
    int lbo = __builtin_amdgcn_readfirstlane((wave << 6) + i * 512);
    if (u < 4576) {
      int part = (u >= 2288) ? 1 : 0;
      int qq = u - part * 2288;
      int pc = qq / 22;
      int dloc = qq - pc * 22;
      int panel = pc >> 1, icq = pc & 1;
      int rr = panel / 13, cc = panel - rr * 13;
      int hh = 2 * bx + rr - 1, ww = cc - 1;
      bool ok = (hh >= 0) & (hh < 11) & (ww >= 0) & (ww < 11);
      if (ok) {
        const unsigned short* srcp = part ? pin_lo : pin_hi;
        const unsigned short* g =
            &srcp[(((size_t)b * 121 + hh * 11 + ww) * 134 + d16 * 16 + dloc) *
                      16 +
                  icq * 8];
        __builtin_amdgcn_global_load_lds((const gu32*)g,
                                         (lu32*)&lds[(size_t)lbo * 8], 16, 0,
                                         0);
      } else {
        u16x8 z = {0, 0, 0, 0, 0, 0, 0, 0};
        *(u16x8*)&lds[(size_t)u * 8] = z;
      }
    }
  }
  float bias_r[4], alr[4];
#pragma unroll
  for (int r = 0; r < 4; ++r) {
    bias_r[r] = bias[q * 4 + r];
    alr[r] = al[(q * 4 + r) * 128 + d16 * 16 + n];
  }
  __syncthreads();

  const int wl0 = wg * 3;
  int cb[5], cbk[5];
  const int base_qn = (q & 1) * 176 + n * 8 + hs * 4576;
  const int kdh = (lane & 32) ? 8 : 0;
#pragma unroll
  for (int j = 0; j < 5; ++j) {
    int colj = wl0 + j;
    if (colj > 12) colj = 12;
    cb[j] = base_qn + colj * 352;
    cbk[j] = cb[j] + kdh;
  }

  float4v acc[3];
#pragma unroll
  for (int tt = 0; tt < 3; ++tt) acc[tt] = (float4v){0.f, 0.f, 0.f, 0.f};

#pragma unroll
  for (int kh = 0; kh < 3; ++kh) {
#pragma unroll
    for (int kdp = 0; kdp < 4; ++kdp) {
      half8 whi[5], wlo[5];
#pragma unroll
      for (int j = 0; j < 5; ++j) {
        int a = ((kdp < 3) ? cbk[j] : cb[j]) + kh * 4576 + kdp * 16;
        whi[j] = *(const half8*)&lds[a];
        wlo[j] = *(const half8*)&lds[a + LHALF];
      }
#pragma unroll
      for (int kw = 0; kw < 3; ++kw) {
        const int c2 = (kh * 4 + kdp) * 3 + kw;
        half8 ahi = *(const half8*)&arep[((c2 * 2 + 0) * 64 + lane) * 8];
        half8 alo = *(const half8*)&arep[((c2 * 2 + 1) * 64 + lane) * 8];
#pragma unroll
        for (int tt = 0; tt < 3; ++tt) {
          const int jj = tt + kw;
          acc[tt] = __builtin_amdgcn_mfma_f32_16x16x32_f16(ahi, whi[jj],
                                                           acc[tt], 0, 0, 0);
          acc[tt] = __builtin_amdgcn_mfma_f32_16x16x32_f16(ahi, wlo[jj],
                                                           acc[tt], 0, 0, 0);
          acc[tt] = __builtin_amdgcn_mfma_f32_16x16x32_f16(alo, whi[jj],
                                                           acc[tt], 0, 0, 0);
        }
      }
    }
  }

#pragma unroll
  for (int tt = 0; tt < 3; ++tt) {
    const int wl = wg * 3 + tt;
    if (h < 11 && wl < 11) {
      const int p = h * 11 + wl;
      float fr[4];
      u16x4 hi4, lo4;
#pragma unroll
      for (int r = 0; r < 4; ++r) {
        float sv = fmaxf(acc[tt][r] * (1.f / 65536.f) + bias_r[r], 0.f);
        fr[r] = sv * alr[r];
        if (WRITE_PK) {
          float s = sv * 256.f;
          _Float16 hh = (_Float16)s;
          HU a, bb;
          a.h = hh;
          bb.h = (_Float16)(s - (float)hh);
          hi4[r] = a.u;
          lo4[r] = bb.u;
        }
      }
      if (WRITE_PK) {
        size_t base =
            (((size_t)b * 121 + p) * 134 + d16 * 16 + n + 3) * 16 + q * 4;
        *(u16x4*)&pout_hi[base] = hi4;
        *(u16x4*)&pout_lo[base] = lo4;
        u16x4 z = {0, 0, 0, 0};
        if (d16 == 0 && n < 3) {
          size_t hb = (((size_t)b * 121 + p) * 134 + n) * 16 + q * 4;
          *(u16x4*)&pout_hi[hb] = z;
          *(u16x4*)&pout_lo[hb] = z;
        }
        if (d16 == 7 && n >= 13) {
          size_t hb = (((size_t)b * 121 + p) * 134 + n + 118) * 16 + q * 4;
          *(u16x4*)&pout_hi[hb] = z;
          *(u16x4*)&pout_lo[hb] = z;
        }
      }
#pragma unroll
      for (int r = 0; r < 4; ++r) {
        float v = fr[r];
        v += __shfl_xor(v, 1, 64);
        v += __shfl_xor(v, 2, 64);
        v += __shfl_xor(v, 4, 64);
        v += __shfl_xor(v, 8, 64);
        if (n == 0)
          fpart[(((size_t)d16 * 64 + b) * 16 + q * 4 + r) * 121 + p] = v;
      }
    }
  }
}

// ---------------- sp path (+sa side-outs, +f4/f5 recompute in LDS) ---------
__global__ __launch_bounds__(128) void sp_prep_kernel(
    const float* __restrict__ f1, const float* __restrict__ fpart1,
    const float* __restrict__ fpart2, const float* __restrict__ x,
    const float* __restrict__ wrep2d, const float* __restrict__ b2d45,
    const float* __restrict__ seg_w, const float* __restrict__ seg_b,
    const float* __restrict__ so_w, const float* __restrict__ so_b,
    const float* __restrict__ sp_wa, const float* __restrict__ sp_ba,
    const float* __restrict__ sp_wb, const float* __restrict__ sp_bb,
    const float* __restrict__ sp_sw, const float* __restrict__ sp_sb,
    float* __restrict__ sa_sd, float* __restrict__ sp_sd) {
  const int b = blockIdx.x, i = blockIdx.y;
  const int t = threadIdx.x;
  __shared__ float fl[16 * 121];
  __shared__ float buf[16 * 121];
  __shared__ float act[121];
  __shared__ float diffs[121];
  __shared__ int sel[5];
  __shared__ float s7[7], xc7[7];
  __shared__ float P[2][7][7];
  __shared__ float y1[16][9];
  __shared__ float y2[16];

  {
    float* ldst = (i < 3) ? fl : buf;
    if (i == 0) {
      const float* fb = f1 + (size_t)b * 16 * 121;
      for (int idx = t; idx < 16 * 121; idx += 128) ldst[idx] = fb[idx];
    } else {
      const float* fp0 = (i == 1) ? fpart1 : fpart2;
      const size_t boff = (size_t)b * 16 * 121;
      for (int idx = t; idx < 16 * 121; idx += 128) {
        float s = 0.f;
#pragma unroll
        for (int d16 = 0; d16 < 8; ++d16)  // fixed order -> deterministic
          s += fp0[(size_t)d16 * F_SLICE + boff + idx];
        ldst[idx] = fmaxf(s, 0.f);
      }
    }
  }
  __syncthreads();

#define CONV2D_LAYER(SRC, DST, L)                                        \
  if (t < 121) {                                                         \
    int h_ = t / 11, w_ = t - h_ * 11;                                   \
    float a_[16];                                                        \
    _Pragma("unroll") for (int o = 0; o < 16; ++o) a_[o] =               \
        b2d45[(L)*16 + o];                                               \
    for (int ic = 0; ic < 16; ++ic) {                                    \
      _Pragma("unroll") for (int u = 0; u < 3; ++u) {                    \
        int hh_ = h_ + u - 1;                                            \
        _Pragma("unroll") for (int v = 0; v < 3; ++v) {                  \
          int ww_ = w_ + v - 1;                                          \
          float val_ = (hh_ >= 0 && hh_ < 11 && ww_ >= 0 && ww_ < 11)    \
                           ? (SRC)[ic * 121 + hh_ * 11 + ww_]            \
                           : 0.f;                                        \
          const float* wp_ =                                             \
              wrep2d + (((L)*16 + ic) * 9 + u * 3 + v) * 16;             \
          float wr_[16];                                                 \
          _Pragma("unroll") for (int o = 0; o < 16; ++o) wr_[o] = wp_[o];\
          _Pragma("unroll") for (int o = 0; o < 16; ++o) a_[o] =         \
              fmaf(val_, wr_[o], a_[o]);                                 \
        }                                                                \
      }                                                                  \
    }                                                                    \
    _Pragma("unroll") for (int o = 0; o < 16; ++o)(DST)[o * 121 + t] =   \
        fmaxf(a_[o], 0.f);                                               \
  }

  if (i >= 3) {
    CONV2D_LAYER(buf, fl, 0)
    __syncthreads();
    if (i == 4) {
      CONV2D_LAYER(fl, buf, 1)
      __syncthreads();
    }
  }
  const float* F = (i == 4) ? buf : fl;

  if (t < 16) {
    float s = so_b[i * 16 + t];
    const float* swp = so_w + (i * 16 + t) * 16;
    for (int c = 0; c < 16; ++c) s += F[c * 121 + 60] * swp[c];
    sa_sd[((size_t)i * 64 + b) * 16 + t] = s;
  }

  if (t < 121) {
    int h = t / 11, w = t - h * 11;
    float a = seg_b[i];
    const float* sw = seg_w + i * 144;
    for (int ic = 0; ic < 16; ++ic) {
      float w9[9];
#pragma unroll
      for (int j = 0; j < 9; ++j) w9[j] = sw[ic * 9 + j];
#pragma unroll
      for (int u = 0; u < 3; ++u) {
        int hh = h + u - 1;
#pragma unroll
        for (int v = 0; v < 3; ++v) {
          int ww = w + v - 1;
          if (hh >= 0 && hh < 11 && ww >= 0 && ww < 11)
            a = fmaf(F[ic * 121 + hh * 11 + ww], w9[u * 3 + v], a);
        }
      }
    }
    act[t] = a;
  }
  __syncthreads();
  if (t < 121) diffs[t] = fabsf(act[t] - act[60]);
  __syncthreads();

  for (int k = 0; k < 5; ++k) {
    if (t < 64) {
      float d0 = diffs[t];
      int i0 = t;
      float d1 = (t + 64 < 121) ? diffs[t + 64] : 3.0e38f;
      if (d1 < d0) { d0 = d1; i0 = t + 64; }
#pragma unroll
      for (int off = 32; off; off >>= 1) {
        float od = __shfl_down(d0, off, 64);
        int oi = __shfl_down(i0, off, 64);
        if (od < d0 || (od == d0 && oi < i0)) { d0 = od; i0 = oi; }
      }
      if (t == 0) {
        sel[k] = i0;
        diffs[i0] = 3.0e38f;
      }
    }
    __syncthreads();
  }

  if (t < 7) {
    const float* xb = x + (size_t)b * 15488;  // x[b][d][p]
    float s = 0.f;
    for (int k = 0; k < 5; ++k) s += xb[(61 + t) * 121 + sel[k]];
    s7[t] = s;
    xc7[t] = xb[(61 + t) * 121 + 60];
  }
  __syncthreads();
  if (t < 49) {
    int r = t / 7, c = t - r * 7;
    float d0 = s7[c];
    if (fabsf(d0) < 0.01f) d0 = 0.01f;
    float d1 = xc7[c];
    if (fabsf(d1) < 0.01f) d1 = 0.01f;
    P[0][r][c] = s7[r] / d0;
    P[1][r][c] = xc7[r] / d1;
  }
  __syncthreads();
  for (int item = t; item < 144; item += 128) {
    int ch = item / 9, pos = item - ch * 9;
    int a0 = pos / 3, b0 = pos - a0 * 3;
    float a = sp_ba[i * 16 + ch];
    const float* wa = sp_wa + ((size_t)(i * 16 + ch) * 2) * 9;
#pragma unroll
    for (int icc = 0; icc < 2; ++icc)
#pragma unroll
      for (int u = 0; u < 3; ++u)
#pragma unroll
        for (int v = 0; v < 3; ++v)
          a = fmaf(P[icc][2 * a0 + u][2 * b0 + v], wa[icc * 9 + u * 3 + v], a);
    y1[ch][pos] = fmaxf(a, 0.f);
  }
  __syncthreads();
  if (t < 16) {
    float a = sp_bb[i * 16 + t];
    const float* wb = sp_wb + (size_t)(i * 16 + t) * 16 * 9;
    for (int ch = 0; ch < 16; ++ch)
#pragma unroll
      for (int pos = 0; pos < 9; ++pos)
        a = fmaf(y1[ch][pos], wb[ch * 9 + pos], a);
    y2[t] = fmaxf(a, 0.f);
  }
  __syncthreads();
  if (t < 16) {
    float a = sp_sb[i * 16 + t];
    const float* swp = sp_sw + (size_t)(i * 16 + t) * 16;
    for (int ch = 0; ch < 16; ++ch) a = fmaf(y2[ch], swp[ch], a);
    sp_sd[((size_t)i * 64 + b) * 16 + t] = a;
  }
}

// ---------------- final fuse ------------------------------------------------
__global__ __launch_bounds__(256) void fuse_kernel(
    const float* __restrict__ sa_sd, const float* __restrict__ sp_sd,
    const float* __restrict__ fp, float* __restrict__ out) {
  int g = blockIdx.x * 256 + threadIdx.x;
  if (g >= 1024) return;
  int b = g >> 4, o = g & 15;
  float tot = 0.f;
  for (int i = 0; i < 5; ++i) {
    tot += fp[i] * sa_sd[((size_t)i * 64 + b) * 16 + o];
    tot += fp[5 + i] * sp_sd[((size_t)i * 64 + b) * 16 + o];
  }
  out[g] = tot;
}

extern "C" void kernel_launch(void* const* d_in, const int* in_sizes, int n_in,
                              void* d_out, int out_size, void* d_ws,
                              size_t ws_size, hipStream_t stream) {
  const float* x = (const float*)d_in[0];
  const float* w3d1 = (const float*)d_in[1];
  const float* b3d1 = (const float*)d_in[2];
  const float* w3d23 = (const float*)d_in[3];
  const float* b3d23 = (const float*)d_in[4];
  const float* cpr_w = (const float*)d_in[5];
  const float* w2d45 = (const float*)d_in[6];
  const float* b2d45 = (const float*)d_in[7];
  const float* seg_w = (const float*)d_in[8];
  const float* seg_b = (const float*)d_in[9];
  const float* so_w = (const float*)d_in[10];
  const float* so_b = (const float*)d_in[11];
  const float* sp_wa = (const float*)d_in[12];
  const float* sp_ba = (const float*)d_in[13];
  const float* sp_wb = (const float*)d_in[14];
  const float* sp_bb = (const float*)d_in[15];
  const float* sp_sw = (const float*)d_in[16];
  const float* sp_sb = (const float*)d_in[17];
  const float* fpar = (const float*)d_in[18];

  float* ws = (float*)d_ws;
  float* a_sm = ws;                      // 6144 f
  float* f1 = a_sm + 6144;               // F_SLICE f
  float* fpart1 = f1 + F_SLICE;          // 8*F_SLICE f
  float* fpart2 = fpart1 + 8 * F_SLICE;  // 8*F_SLICE f
  float* sp_sd = fpart2 + 8 * F_SLICE;   // 5120 f
  float* sa_sd = sp_sd + 5120;           // 5120 f
  float* wrep1 = sa_sd + 5120;           // 1024 f
  float* wrep2d = wrep1 + 1024;          // 4608 f
  unsigned short* pk1h = (unsigned short*)(wrep2d + 4608);
  unsigned short* pk1l = pk1h + PKE;
  unsigned short* pk2h = pk1l + PKE;
  unsigned short* pk2l = pk2h + PKE;
  unsigned short* arep = pk2l + PKE;     // 2*AREP_CV u16

  prep_kernel<<<358, 256, 0, stream>>>(cpr_w, w3d1, w2d45, w3d23, a_sm, wrep1,
                                       wrep2d, arep);

  conv1_kernel<<<dim3(33, 64), 256, 0, stream>>>(x, wrep1, b3d1, a_sm, pk1h,
                                                 pk1l, f1);
  conv_mfma_kernel<true><<<dim3(6, 8, 64), 512, 0, stream>>>(
      pk1h, pk1l, arep, b3d23, a_sm + 2048, pk2h, pk2l, fpart1);
  conv_mfma_kernel<false><<<dim3(6, 8, 64), 512, 0, stream>>>(
      pk2h, pk2l, arep + AREP_CV, b3d23 + 16, a_sm + 4096, nullptr, nullptr,
      fpart2);

  sp_prep_kernel<<<dim3(64, 5), 128, 0, stream>>>(
      f1, fpart1, fpart2, x, wrep2d, b2d45, seg_w, seg_b, so_w, so_b, sp_wa,
      sp_ba, sp_wb, sp_bb, sp_sw, sp_sb, sa_sd, sp_sd);
  fuse_kernel<<<4, 256, 0, stream>>>(sa_sd, sp_sd, fpar, (float*)d_out);
}